// Round 23
// baseline (64.800 us; speedup 1.0000x reference)
//
#include <hip/hip_runtime.h>
#include <hip/hip_bf16.h>

#define L  512
#define F  64
#define P  32
#define ZO 128
#define JCH 16   // j-chunk for k_lnT
#define LZ (L * ZO)

constexpr float EPS_LN   = 1e-10f;
constexpr float EPS_NORM = 1e-3f;

typedef short s16x8 __attribute__((ext_vector_type(8)));   // 8 bf16 (A/B frag)
typedef float f32x4 __attribute__((ext_vector_type(4)));   // C/D frag

// ---------------------------------------------------------------------------
// Kernel 1 (Round-23, fused LN+proj+T): each block recomputes the 16 b-rows
// it needs (LN + Wb-proj, 16x redundant across sx but only ~256 FMA/wave,
// hidden under Wz loads), then the k_T main loop reads b from LDS. Blocks
// with sx==0 additionally emit the bf16 a-rows of their i0-tile (by*16).
// Saves the k_ln launch + b's global round-trip.
// ---------------------------------------------------------------------------
__global__ __launch_bounds__(256) void k_lnT(
    const float* __restrict__ M, const float* __restrict__ mask,
    const float* __restrict__ gamma, const float* __restrict__ beta,
    const float* __restrict__ Wa, const float* __restrict__ ba,
    const float* __restrict__ Wb, const float* __restrict__ bb,
    const float* __restrict__ Wz,
    __hip_bfloat16* __restrict__ Tbf, __hip_bfloat16* __restrict__ abf) {
  __shared__ float y_sh[4][F];     // per-wave y buffer (1 KB)
  __shared__ float b_lds[JCH][P];  // 2 KB
  const int t    = threadIdx.x;
  const int wave = t >> 6;
  const int lane = t & 63;
  const int j0   = blockIdx.y * JCH;

  // ---- Phase A: LN + b-proj for rows j0..j0+15 (wave w -> rows w*4..w*4+3)
  #pragma unroll
  for (int rr = 0; rr < 4; ++rr) {
    const int row = j0 + wave * 4 + rr;
    const float m = M[row * F + lane];
    float s = m;
    #pragma unroll
    for (int o = 32; o >= 1; o >>= 1) s += __shfl_xor(s, o);
    const float mean = s * (1.0f / F);
    const float d = m - mean;
    float v = d * d;
    #pragma unroll
    for (int o = 32; o >= 1; o >>= 1) v += __shfl_xor(v, o);
    const float rstd = rsqrtf(v * (1.0f / F) + EPS_LN);
    y_sh[wave][lane] = d * rstd * gamma[lane] + beta[lane];
    // same-wave LDS write->read: lockstep wave, lgkmcnt-ordered, no barrier
    const int p = lane & (P - 1);
    float acc = 0.f;
    #pragma unroll 8
    for (int f = 0; f < F; ++f) acc += y_sh[wave][f] * Wb[p * F + f];
    if (lane < P) b_lds[wave * 4 + rr][p] = (acc + bb[p]) * mask[row];
  }

  // ---- Phase A2: blocks sx==0 emit bf16 a-rows for i0-tile = by*16
  if (blockIdx.x == 0) {
    const int i0 = blockIdx.y * 16;
    #pragma unroll
    for (int rr = 0; rr < 4; ++rr) {
      const int row = i0 + wave * 4 + rr;
      const float m = M[row * F + lane];
      float s = m;
      #pragma unroll
      for (int o = 32; o >= 1; o >>= 1) s += __shfl_xor(s, o);
      const float mean = s * (1.0f / F);
      const float d = m - mean;
      float v = d * d;
      #pragma unroll
      for (int o = 32; o >= 1; o >>= 1) v += __shfl_xor(v, o);
      const float rstd = rsqrtf(v * (1.0f / F) + EPS_LN);
      y_sh[wave][lane] = d * rstd * gamma[lane] + beta[lane];
      const int p = lane & (P - 1);
      float acc = 0.f;
      #pragma unroll 8
      for (int f = 0; f < F; ++f) acc += y_sh[wave][f] * Wa[p * F + f];
      if (lane < P)
        abf[row * P + p] = __float2bfloat16((acc + ba[p]) * mask[row]);
    }
  }

  __syncthreads();

  // ---- Phase B: T[j][seg] = sum_e b[j][e] * Wz[seg*32+e], bf16 out
  const int seg = blockIdx.x * 256 + t;   // 0..4095
  float4 w[8];
  const float4* wp = (const float4*)(Wz + (size_t)seg * 32);
  #pragma unroll
  for (int q = 0; q < 8; ++q) w[q] = wp[q];

  #pragma unroll 2
  for (int jj = 0; jj < JCH; ++jj) {
    float acc0 = 0.f, acc1 = 0.f, acc2 = 0.f, acc3 = 0.f;
    #pragma unroll
    for (int q = 0; q < 8; ++q) {
      acc0 += w[q].x * b_lds[jj][q * 4 + 0];
      acc1 += w[q].y * b_lds[jj][q * 4 + 1];
      acc2 += w[q].z * b_lds[jj][q * 4 + 2];
      acc3 += w[q].w * b_lds[jj][q * 4 + 3];
    }
    Tbf[(size_t)(j0 + jj) * (ZO * P) + seg] =
        __float2bfloat16((acc0 + acc1) + (acc2 + acc3));
  }
}

// ---------------------------------------------------------------------------
// Kernel 2 (k_z, byte-identical to R22 best = 38.98us): MFMA GEMM, moving
// 32-MB write front (grid (256,32) i0-slowest, 4 q/wave), bijective XCD
// swizzle on bx. Fragment maps (R16-verified): A row=lane&15,
// k=(lane>>4)*8+e; B col=lane&15 (->n), same k; D col=lane&15,
// row=(lane>>4)*4+reg (->i).
// ---------------------------------------------------------------------------
__global__ __launch_bounds__(256, 8) void k_z(
    const __hip_bfloat16* __restrict__ abf,  // [512][32]
    const float* __restrict__ mask,
    const __hip_bfloat16* __restrict__ Tbf,  // [65536][32]
    const float* __restrict__ bz,
    float* __restrict__ Z) {
  const int t    = threadIdx.x;
  const int lane = t & 63;
  const int w    = t >> 6;
  const int r16  = lane & 15;
  const int kg   = lane >> 4;
  const int bx   = blockIdx.x;
  const int sx   = (bx & 7) * 32 + (bx >> 3);   // bijective XCD swizzle
  const int ngg  = sx & 63;
  const int qc   = sx >> 6;                // 0..3 -> q in [qc*4, qc*4+4)
  const int i0   = blockIdx.y * 16;
  const int ng   = ngg * 4 + w;            // 0..255
  const int n0   = ng * 256;

  const s16x8 afrag =
      *(const s16x8*)((const short*)abf + (size_t)(i0 + r16) * P + kg * 8);

  const int jj = (n0 >> 7) + (qc >> 1);
  const float mj = mask[jj];
  const float4 mi4 = *(const float4*)(mask + i0 + kg * 4);
  float inv[4];
  inv[0] = __builtin_amdgcn_rcpf(EPS_NORM + mi4.x * mj);
  inv[1] = __builtin_amdgcn_rcpf(EPS_NORM + mi4.y * mj);
  inv[2] = __builtin_amdgcn_rcpf(EPS_NORM + mi4.z * mj);
  inv[3] = __builtin_amdgcn_rcpf(EPS_NORM + mi4.w * mj);

  float bzr[4];
  #pragma unroll
  for (int k2 = 0; k2 < 4; ++k2)
    bzr[k2] = bz[(((qc * 4 + k2) & 7) * 16) + r16];

  const short* tb = (const short*)Tbf + (size_t)(n0 + r16) * P + kg * 8;
  float* zb = Z + (size_t)(i0 + kg * 4) * LZ + n0 + r16;

  #pragma unroll
  for (int k2 = 0; k2 < 4; ++k2) {
    const int q = qc * 4 + k2;
    const s16x8 bfrag = *(const s16x8*)(tb + (size_t)q * 16 * P);
    f32x4 acc = {0.f, 0.f, 0.f, 0.f};
    acc = __builtin_amdgcn_mfma_f32_16x16x32_bf16(afrag, bfrag, acc, 0, 0, 0);
    const float bzv = bzr[k2];
    float* zq = zb + q * 16;
    zq[(size_t)0 * LZ] = (acc[0] + bzv) * inv[0];
    zq[(size_t)1 * LZ] = (acc[1] + bzv) * inv[1];
    zq[(size_t)2 * LZ] = (acc[2] + bzv) * inv[2];
    zq[(size_t)3 * LZ] = (acc[3] + bzv) * inv[3];
  }
}

// ---------------------------------------------------------------------------
extern "C" void kernel_launch(void* const* d_in, const int* in_sizes, int n_in,
                              void* d_out, int out_size, void* d_ws, size_t ws_size,
                              hipStream_t stream) {
  const float* M     = (const float*)d_in[0];
  const float* mask  = (const float*)d_in[1];
  const float* gamma = (const float*)d_in[2];
  const float* beta  = (const float*)d_in[3];
  const float* Wa    = (const float*)d_in[4];
  const float* ba    = (const float*)d_in[5];
  const float* Wb    = (const float*)d_in[6];
  const float* bb    = (const float*)d_in[7];
  const float* Wz    = (const float*)d_in[8];
  const float* bz    = (const float*)d_in[9];

  float* Z = (float*)d_out;
  __hip_bfloat16* Tbf = (__hip_bfloat16*)d_ws;               // 4 MB
  __hip_bfloat16* abf = Tbf + (size_t)L * ZO * P;            // 32 KB

  k_lnT<<<dim3((ZO * P) / 256, L / JCH), 256, 0, stream>>>(
      M, mask, gamma, beta, Wa, ba, Wb, bb, Wz, Tbf, abf);
  k_z<<<dim3(256, 32), 256, 0, stream>>>(abf, mask, Tbf, bz, Z);
}

// Round 24
// 38.872 us; speedup vs baseline: 1.6670x; 1.6670x over previous
//
#include <hip/hip_runtime.h>
#include <hip/hip_bf16.h>

#define L  512
#define F  64
#define P  32
#define ZO 128
#define JCH 16   // j-chunk for k_T
#define LZ (L * ZO)

constexpr float EPS_LN   = 1e-10f;
constexpr float EPS_NORM = 1e-3f;

typedef short s16x8 __attribute__((ext_vector_type(8)));   // 8 bf16 (A/B frag)
typedef float f32x4 __attribute__((ext_vector_type(4)));   // C/D frag

// ---------------------------------------------------------------------------
// Kernel 1: LayerNorm + two 64->32 projections; also emits bf16 copy of a.
// (~2us) R23 proved fusing this into k_T costs +26us -- keep separate.
// ---------------------------------------------------------------------------
__global__ __launch_bounds__(256) void k_ln_proj(
    const float* __restrict__ M, const float* __restrict__ mask,
    const float* __restrict__ gamma, const float* __restrict__ beta,
    const float* __restrict__ Wa, const float* __restrict__ ba,
    const float* __restrict__ Wb, const float* __restrict__ bb,
    float* __restrict__ a, float* __restrict__ b,
    __hip_bfloat16* __restrict__ abf) {
  __shared__ float y_lds[4][F];
  const int wave = threadIdx.x >> 6;
  const int lane = threadIdx.x & 63;
  const int row  = blockIdx.x * 4 + wave;

  float m = M[row * F + lane];
  float s = m;
  #pragma unroll
  for (int o = 32; o >= 1; o >>= 1) s += __shfl_xor(s, o);
  float mean = s * (1.0f / F);
  float d = m - mean;
  float v = d * d;
  #pragma unroll
  for (int o = 32; o >= 1; o >>= 1) v += __shfl_xor(v, o);
  float rstd = rsqrtf(v * (1.0f / F) + EPS_LN);
  float y = d * rstd * gamma[lane] + beta[lane];
  y_lds[wave][lane] = y;
  __syncthreads();

  const float mk = mask[row];
  const float* W    = (lane < P) ? Wa : Wb;
  const float* bias = (lane < P) ? ba : bb;
  const int p = lane & (P - 1);
  float acc = 0.f;
  #pragma unroll 8
  for (int f = 0; f < F; ++f) acc += y_lds[wave][f] * W[p * F + f];
  acc = (acc + bias[p]) * mk;
  if (lane < P) {
    a[row * P + p]   = acc;
    abf[row * P + p] = __float2bfloat16(acc);
  } else {
    b[row * P + p] = acc;
  }
}

// ---------------------------------------------------------------------------
// Kernel 2: T[j][z][d] = sum_e b[j][e] * Wz[z*1024 + d*32 + e], bf16 out.
// (~4.5us, frozen)
// ---------------------------------------------------------------------------
__global__ __launch_bounds__(256) void k_T(
    const float* __restrict__ b, const float* __restrict__ Wz,
    __hip_bfloat16* __restrict__ Tbf) {
  const int seg = blockIdx.x * 256 + threadIdx.x;   // 0..4095
  const int j0  = blockIdx.y * JCH;

  float4 w[8];
  const float4* wp = (const float4*)(Wz + (size_t)seg * 32);
  #pragma unroll
  for (int q = 0; q < 8; ++q) w[q] = wp[q];

  #pragma unroll 2
  for (int jj = 0; jj < JCH; ++jj) {
    const float* __restrict__ br = b + (size_t)(j0 + jj) * P;  // uniform
    float acc0 = 0.f, acc1 = 0.f, acc2 = 0.f, acc3 = 0.f;
    #pragma unroll
    for (int q = 0; q < 8; ++q) {
      acc0 += w[q].x * br[q * 4 + 0];
      acc1 += w[q].y * br[q * 4 + 1];
      acc2 += w[q].z * br[q * 4 + 2];
      acc3 += w[q].w * br[q * 4 + 3];
    }
    Tbf[(size_t)(j0 + jj) * (ZO * P) + seg] =
        __float2bfloat16((acc0 + acc1) + (acc2 + acc3));
  }
}

// ---------------------------------------------------------------------------
// Kernel 3 (R22 best = 38.98us): MFMA GEMM, moving 32-MB write front
// (grid (256,32) i0-slowest, 4 q/wave), bijective XCD swizzle on bx.
// Confirmed levers: MFMA (-15us), write-window 134->32MB (-2us).
// Null-tested: store width/NT/plain/segmentation, LDS transpose (block
// and wave level), occupancy 16<->32 waves/CU, scalar vs vector a-loads,
// XCD swizzle (kept, free), LN/T fusion (regressed).
// Fragment maps (R16-verified): A row=lane&15, k=(lane>>4)*8+e; B
// col=lane&15 (->n), same k; D col=lane&15, row=(lane>>4)*4+reg (->i).
// ---------------------------------------------------------------------------
__global__ __launch_bounds__(256, 8) void k_z(
    const __hip_bfloat16* __restrict__ abf,  // [512][32]
    const float* __restrict__ mask,
    const __hip_bfloat16* __restrict__ Tbf,  // [65536][32]
    const float* __restrict__ bz,
    float* __restrict__ Z) {
  const int t    = threadIdx.x;
  const int lane = t & 63;
  const int w    = t >> 6;
  const int r16  = lane & 15;
  const int kg   = lane >> 4;
  const int bx   = blockIdx.x;
  const int sx   = (bx & 7) * 32 + (bx >> 3);   // bijective XCD swizzle
  const int ngg  = sx & 63;
  const int qc   = sx >> 6;                // 0..3 -> q in [qc*4, qc*4+4)
  const int i0   = blockIdx.y * 16;
  const int ng   = ngg * 4 + w;            // 0..255
  const int n0   = ng * 256;

  const s16x8 afrag =
      *(const s16x8*)((const short*)abf + (size_t)(i0 + r16) * P + kg * 8);

  const int jj = (n0 >> 7) + (qc >> 1);
  const float mj = mask[jj];
  const float4 mi4 = *(const float4*)(mask + i0 + kg * 4);
  float inv[4];
  inv[0] = __builtin_amdgcn_rcpf(EPS_NORM + mi4.x * mj);
  inv[1] = __builtin_amdgcn_rcpf(EPS_NORM + mi4.y * mj);
  inv[2] = __builtin_amdgcn_rcpf(EPS_NORM + mi4.z * mj);
  inv[3] = __builtin_amdgcn_rcpf(EPS_NORM + mi4.w * mj);

  float bzr[4];
  #pragma unroll
  for (int k2 = 0; k2 < 4; ++k2)
    bzr[k2] = bz[(((qc * 4 + k2) & 7) * 16) + r16];

  const short* tb = (const short*)Tbf + (size_t)(n0 + r16) * P + kg * 8;
  float* zb = Z + (size_t)(i0 + kg * 4) * LZ + n0 + r16;

  #pragma unroll
  for (int k2 = 0; k2 < 4; ++k2) {
    const int q = qc * 4 + k2;
    const s16x8 bfrag = *(const s16x8*)(tb + (size_t)q * 16 * P);
    f32x4 acc = {0.f, 0.f, 0.f, 0.f};
    acc = __builtin_amdgcn_mfma_f32_16x16x32_bf16(afrag, bfrag, acc, 0, 0, 0);
    const float bzv = bzr[k2];
    float* zq = zb + q * 16;
    zq[(size_t)0 * LZ] = (acc[0] + bzv) * inv[0];
    zq[(size_t)1 * LZ] = (acc[1] + bzv) * inv[1];
    zq[(size_t)2 * LZ] = (acc[2] + bzv) * inv[2];
    zq[(size_t)3 * LZ] = (acc[3] + bzv) * inv[3];
  }
}

// ---------------------------------------------------------------------------
extern "C" void kernel_launch(void* const* d_in, const int* in_sizes, int n_in,
                              void* d_out, int out_size, void* d_ws, size_t ws_size,
                              hipStream_t stream) {
  const float* M     = (const float*)d_in[0];
  const float* mask  = (const float*)d_in[1];
  const float* gamma = (const float*)d_in[2];
  const float* beta  = (const float*)d_in[3];
  const float* Wa    = (const float*)d_in[4];
  const float* ba    = (const float*)d_in[5];
  const float* Wb    = (const float*)d_in[6];
  const float* bb    = (const float*)d_in[7];
  const float* Wz    = (const float*)d_in[8];
  const float* bz    = (const float*)d_in[9];

  float* Z = (float*)d_out;
  float* a = (float*)d_ws;                         // 512*32 f32 = 64 KB
  float* b = a + L * P;                            // 64 KB
  __hip_bfloat16* Tbf = (__hip_bfloat16*)(b + L * P);        // 4 MB
  __hip_bfloat16* abf = Tbf + (size_t)L * ZO * P;            // 32 KB

  k_ln_proj<<<L / 4, 256, 0, stream>>>(M, mask, gamma, beta, Wa, ba, Wb, bb,
                                       a, b, abf);
  k_T<<<dim3((ZO * P) / 256, L / JCH), 256, 0, stream>>>(b, Wz, Tbf);
  k_z<<<dim3(256, 32), 256, 0, stream>>>(abf, mask, Tbf, bz, Z);
}